// Round 1
// baseline (93.299 us; speedup 1.0000x reference)
//
#include <hip/hip_runtime.h>
#include <math.h>

// Problem constants
#define B_  32
#define C_  256
#define H_  56
#define W_  56
#define CR_ 64          // C/RED
#define HW_ (H_*W_)     // 3136
#define BC_ (B_*C_)     // 8192

// ---------------------------------------------------------------------------
// Kernel 1: global average pool. One block per (b,c) plane.
// ---------------------------------------------------------------------------
__global__ __launch_bounds__(256) void gap_kernel(const float* __restrict__ x,
                                                  float* __restrict__ gap) {
    const int bc = blockIdx.x;
    const float4* p4 = (const float4*)(x + (size_t)bc * HW_);
    float s = 0.f;
    // 3136 floats = 784 float4
    for (int i = threadIdx.x; i < HW_ / 4; i += 256) {
        float4 v = p4[i];
        s += (v.x + v.y) + (v.z + v.w);
    }
    // wave (64-lane) reduce
    for (int off = 32; off > 0; off >>= 1) s += __shfl_down(s, off, 64);
    __shared__ float ws[4];
    const int lane = threadIdx.x & 63, wid = threadIdx.x >> 6;
    if (lane == 0) ws[wid] = s;
    __syncthreads();
    if (threadIdx.x == 0) {
        float t = (ws[0] + ws[1]) + (ws[2] + ws[3]);
        gap[bc] = t * (1.0f / (float)HW_);
    }
}

// ---------------------------------------------------------------------------
// Kernel 2: MLP (gap->gelu->logits) + softmax over 9 taps.
// One block per batch, 256 threads (one per channel).
// ---------------------------------------------------------------------------
__global__ __launch_bounds__(256) void mlp_kernel(const float* __restrict__ gap,
                                                  const float* __restrict__ w1,
                                                  const float* __restrict__ b1,
                                                  const float* __restrict__ w2,
                                                  const float* __restrict__ b2,
                                                  float* __restrict__ wk) {
    const int b = blockIdx.x;           // 0..31
    __shared__ float g[C_];
    __shared__ float hid[CR_];
    g[threadIdx.x] = gap[b * C_ + threadIdx.x];
    __syncthreads();
    if (threadIdx.x < CR_) {
        const int j = threadIdx.x;
        float acc = b1[j];
        const float* wr = w1 + j * C_;
        #pragma unroll 8
        for (int c = 0; c < C_; ++c) acc += g[c] * wr[c];
        // exact GELU: 0.5*x*(1+erf(x/sqrt(2)))
        hid[j] = 0.5f * acc * (1.0f + erff(acc * 0.7071067811865476f));
    }
    __syncthreads();
    const int c = threadIdx.x;          // channel
    float lg[9];
    float mx = -INFINITY;
    #pragma unroll
    for (int t = 0; t < 9; ++t) {
        const int r = c * 9 + t;
        float acc = b2[r];
        const float* wr = w2 + r * CR_;
        #pragma unroll 8
        for (int k = 0; k < CR_; ++k) acc += hid[k] * wr[k];
        lg[t] = acc;
        mx = fmaxf(mx, acc);
    }
    float den = 0.f;
    #pragma unroll
    for (int t = 0; t < 9; ++t) { lg[t] = expf(lg[t] - mx); den += lg[t]; }
    const float inv = 1.0f / den;
    float* o = wk + ((size_t)b * C_ + c) * 9;
    #pragma unroll
    for (int t = 0; t < 9; ++t) o[t] = lg[t] * inv;
}

// ---------------------------------------------------------------------------
// Kernel 3: per-(b,c) dynamic 3x3 depthwise conv (cross-correlation, zero pad)
// + residual. One block per plane; plane staged in 58x58 zero-haloed LDS.
// ---------------------------------------------------------------------------
__global__ __launch_bounds__(256) void dconv_kernel(const float* __restrict__ x,
                                                    const float* __restrict__ wk,
                                                    float* __restrict__ out) {
    const int bc = blockIdx.x;
    const float* p = x + (size_t)bc * HW_;
    float* o = out + (size_t)bc * HW_;

    __shared__ float sm[58 * 58];
    __shared__ float kw[9];

    // zero-fill (covers the halo)
    for (int i = threadIdx.x; i < 58 * 58; i += 256) sm[i] = 0.f;
    if (threadIdx.x < 9) kw[threadIdx.x] = wk[(size_t)bc * 9 + threadIdx.x];
    __syncthreads();

    // load interior, coalesced global read
    for (int i = threadIdx.x; i < HW_; i += 256) {
        const int y = i / W_, xw = i - y * W_;
        sm[(y + 1) * 58 + (xw + 1)] = p[i];
    }
    __syncthreads();

    const float k0 = kw[0], k1 = kw[1], k2 = kw[2];
    const float k3 = kw[3], k4 = kw[4], k5 = kw[5];
    const float k6 = kw[6], k7 = kw[7], k8 = kw[8];

    for (int i = threadIdx.x; i < HW_; i += 256) {
        const int y = i / W_, xw = i - y * W_;
        const float* c = &sm[y * 58 + xw];   // top-left of 3x3 window
        float v = c[0]   * k0 + c[1]   * k1 + c[2]   * k2
                + c[58]  * k3 + c[59]  * k4 + c[60]  * k5
                + c[116] * k6 + c[117] * k7 + c[118] * k8
                + c[59];                      // residual (center = input pixel)
        o[i] = v;
    }
}

// ---------------------------------------------------------------------------
extern "C" void kernel_launch(void* const* d_in, const int* in_sizes, int n_in,
                              void* d_out, int out_size, void* d_ws, size_t ws_size,
                              hipStream_t stream) {
    const float* x  = (const float*)d_in[0];
    const float* w1 = (const float*)d_in[1];
    const float* b1 = (const float*)d_in[2];
    const float* w2 = (const float*)d_in[3];
    const float* b2 = (const float*)d_in[4];
    float* out = (float*)d_out;

    float* gap = (float*)d_ws;                  // 8192 floats
    float* wk  = gap + BC_;                     // 32*2304 = 73728 floats

    gap_kernel<<<BC_, 256, 0, stream>>>(x, gap);
    mlp_kernel<<<B_, 256, 0, stream>>>(gap, w1, b1, w2, b2, wk);
    dconv_kernel<<<BC_, 256, 0, stream>>>(x, wk, out);
}

// Round 2
// 78.925 us; speedup vs baseline: 1.1821x; 1.1821x over previous
//
#include <hip/hip_runtime.h>
#include <math.h>

// Problem constants
#define B_  32
#define C_  256
#define H_  56
#define W_  56
#define CR_ 64          // C/RED
#define HW_ (H_*W_)     // 3136
#define BC_ (B_*C_)     // 8192

// ---------------------------------------------------------------------------
// Kernel 1: global average pool. One block per (b,c) plane.
// ---------------------------------------------------------------------------
__global__ __launch_bounds__(256) void gap_kernel(const float* __restrict__ x,
                                                  float* __restrict__ gap) {
    const int bc = blockIdx.x;
    const float4* p4 = (const float4*)(x + (size_t)bc * HW_);
    float s = 0.f;
    // 3136 floats = 784 float4
    for (int i = threadIdx.x; i < HW_ / 4; i += 256) {
        float4 v = p4[i];
        s += (v.x + v.y) + (v.z + v.w);
    }
    for (int off = 32; off > 0; off >>= 1) s += __shfl_down(s, off, 64);
    __shared__ float ws[4];
    const int lane = threadIdx.x & 63, wid = threadIdx.x >> 6;
    if (lane == 0) ws[wid] = s;
    __syncthreads();
    if (threadIdx.x == 0) {
        float t = (ws[0] + ws[1]) + (ws[2] + ws[3]);
        gap[bc] = t * (1.0f / (float)HW_);
    }
}

// ---------------------------------------------------------------------------
// Kernel 2: MLP (gap->gelu->logits) + softmax over 9 taps.
// One block per batch, 256 threads (one per channel). float4 weight loads.
// ---------------------------------------------------------------------------
__global__ __launch_bounds__(256) void mlp_kernel(const float* __restrict__ gap,
                                                  const float* __restrict__ w1,
                                                  const float* __restrict__ b1,
                                                  const float* __restrict__ w2,
                                                  const float* __restrict__ b2,
                                                  float* __restrict__ wk) {
    const int b = blockIdx.x;           // 0..31
    __shared__ float g[C_];
    __shared__ float hid[CR_];
    g[threadIdx.x] = gap[b * C_ + threadIdx.x];
    __syncthreads();
    if (threadIdx.x < CR_) {
        const int j = threadIdx.x;
        float acc = b1[j];
        const float4* wr = (const float4*)(w1 + (size_t)j * C_);
        #pragma unroll 8
        for (int q = 0; q < C_ / 4; ++q) {
            float4 w = wr[q];
            acc += w.x * g[4*q] + w.y * g[4*q+1] + w.z * g[4*q+2] + w.w * g[4*q+3];
        }
        // exact GELU: 0.5*x*(1+erf(x/sqrt(2)))
        hid[j] = 0.5f * acc * (1.0f + erff(acc * 0.7071067811865476f));
    }
    __syncthreads();
    const int c = threadIdx.x;          // channel
    float lg[9];
    float mx = -INFINITY;
    #pragma unroll
    for (int t = 0; t < 9; ++t) {
        const int r = c * 9 + t;
        float acc = b2[r];
        const float4* wr = (const float4*)(w2 + (size_t)r * CR_);
        #pragma unroll
        for (int q = 0; q < CR_ / 4; ++q) {
            float4 w = wr[q];
            acc += w.x * hid[4*q] + w.y * hid[4*q+1] + w.z * hid[4*q+2] + w.w * hid[4*q+3];
        }
        lg[t] = acc;
        mx = fmaxf(mx, acc);
    }
    float den = 0.f;
    #pragma unroll
    for (int t = 0; t < 9; ++t) { lg[t] = expf(lg[t] - mx); den += lg[t]; }
    const float inv = 1.0f / den;
    float* o = wk + ((size_t)b * C_ + c) * 9;
    #pragma unroll
    for (int t = 0; t < 9; ++t) o[t] = lg[t] * inv;
}

// ---------------------------------------------------------------------------
// Kernel 3: per-(b,c) dynamic 3x3 depthwise conv + residual.
// Plane staged in LDS (row stride 64, zero halo). Each thread owns one
// column for a 14-row strip; rolling registers -> 3 new LDS reads per
// output row instead of 9, stride-1 lanes (conflict-free).
// ---------------------------------------------------------------------------
__global__ __launch_bounds__(256) void dconv_kernel(const float* __restrict__ x,
                                                    const float* __restrict__ wk,
                                                    float* __restrict__ out) {
    const int bc = blockIdx.x;
    const float* p = x + (size_t)bc * HW_;
    float* o = out + (size_t)bc * HW_;

    // LDS rows 0..57 = image rows -1..56 (halo rows 0,57 zero).
    // Interior image col x -> LDS col x+4 (cols 3 and 60 are zero halo).
    __shared__ float sm[58 * 64];
    __shared__ float kw[9];
    float4* sm4 = (float4*)sm;

    for (int i = threadIdx.x; i < 58 * 16; i += 256)
        sm4[i] = make_float4(0.f, 0.f, 0.f, 0.f);
    if (threadIdx.x < 9) kw[threadIdx.x] = wk[(size_t)bc * 9 + threadIdx.x];
    __syncthreads();

    const float4* p4 = (const float4*)p;
    for (int i = threadIdx.x; i < HW_ / 4; i += 256) {
        const int y = i / 14, xq = i - y * 14;          // 14 float4 per row
        sm4[(y + 1) * 16 + 1 + xq] = p4[i];
    }
    __syncthreads();

    const float k0 = kw[0], k1 = kw[1], k2 = kw[2];
    const float k3 = kw[3], k4 = kw[4], k5 = kw[5];
    const float k6 = kw[6], k7 = kw[7], k8 = kw[8];

    const int xc = threadIdx.x & 63;     // column 0..55 (56..63 idle)
    const int g  = threadIdx.x >> 6;     // row-group 0..3 (14 rows each)
    if (xc < 56) {
        const int y0 = g * 14;
        const float* base = sm + xc + 3;               // cols x-1,x,x+1 -> +0,+1,+2
        const float* r0 = base + (y0) * 64;            // image row y0-1
        const float* r1 = base + (y0 + 1) * 64;        // image row y0
        float a0 = r0[0], a1 = r0[1], a2 = r0[2];
        float b0 = r1[0], b1 = r1[1], b2 = r1[2];
        #pragma unroll
        for (int r = 0; r < 14; ++r) {
            const float* r2 = base + (y0 + 2 + r) * 64; // image row y0+r+1
            const float c0 = r2[0], c1 = r2[1], c2 = r2[2];
            const float v = a0 * k0 + a1 * k1 + a2 * k2
                          + b0 * k3 + b1 * k4 + b2 * k5
                          + c0 * k6 + c1 * k7 + c2 * k8
                          + b1;                          // residual
            o[(y0 + r) * W_ + xc] = v;
            a0 = b0; a1 = b1; a2 = b2;
            b0 = c0; b1 = c1; b2 = c2;
        }
    }
}

// ---------------------------------------------------------------------------
extern "C" void kernel_launch(void* const* d_in, const int* in_sizes, int n_in,
                              void* d_out, int out_size, void* d_ws, size_t ws_size,
                              hipStream_t stream) {
    const float* x  = (const float*)d_in[0];
    const float* w1 = (const float*)d_in[1];
    const float* b1 = (const float*)d_in[2];
    const float* w2 = (const float*)d_in[3];
    const float* b2 = (const float*)d_in[4];
    float* out = (float*)d_out;

    float* gap = (float*)d_ws;                  // 8192 floats
    float* wk  = gap + BC_;                     // 32*2304 = 73728 floats

    gap_kernel<<<BC_, 256, 0, stream>>>(x, gap);
    mlp_kernel<<<B_, 256, 0, stream>>>(gap, w1, b1, w2, b2, wk);
    dconv_kernel<<<BC_, 256, 0, stream>>>(x, wk, out);
}